// Round 1
// baseline (2998.657 us; speedup 1.0000x reference)
//
#include <hip/hip_runtime.h>

#define NN 50000
#define NE 800000
#define DD 128
#define GG 2048
#define EPS 1e-5f

__global__ __launch_bounds__(256) void k_copy(const float4* __restrict__ s,
                                              float4* __restrict__ d, int n4) {
  int i = blockIdx.x * 256 + threadIdx.x;
  if (i < n4) d[i] = s[i];
}

// out[dst] += x[src], 32 lanes per edge, float4 per lane
__global__ __launch_bounds__(256) void k_scatter(const float* __restrict__ x,
                                                 const int* __restrict__ ei,
                                                 float* __restrict__ out) {
  int t = blockIdx.x * 256 + threadIdx.x;
  int e = t >> 5;
  if (e >= NE) return;
  int lane = t & 31;
  int s = ei[e];
  int d = ei[NE + e];
  float4 v = ((const float4*)(x + (size_t)s * DD))[lane];
  float* dp = out + (size_t)d * DD + lane * 4;
  atomicAdd(dp + 0, v.x);
  atomicAdd(dp + 1, v.y);
  atomicAdd(dp + 2, v.z);
  atomicAdd(dp + 3, v.w);
}

// out = relu(bn(A@W + bias)); A:(N,128) W:(128,128), BN folded into alpha/beta
__global__ __launch_bounds__(256) void k_gemm128(const float* __restrict__ A,
                                                 const float* __restrict__ W,
                                                 const float* __restrict__ bias,
                                                 const float* __restrict__ gam,
                                                 const float* __restrict__ bet,
                                                 const float* __restrict__ mu,
                                                 const float* __restrict__ var,
                                                 float* __restrict__ out, int N) {
  __shared__ float Ws[DD * DD];      // 64 KB
  __shared__ float As[16][DD];       // 8 KB
  __shared__ float al[DD], bb[DD];   // 1 KB
  int t = threadIdx.x;
  for (int i = t; i < DD * DD; i += 256) Ws[i] = W[i];
  if (t < DD) {
    float a = gam[t] * rsqrtf(var[t] + EPS);
    al[t] = a;
    bb[t] = (bias[t] - mu[t]) * a + bet[t];
  }
  int row0 = blockIdx.x * 16;
  for (int i = t; i < 16 * 32; i += 256) {
    int r = i >> 5, c4 = i & 31;
    int gr = row0 + r;
    float4 v = (gr < N) ? ((const float4*)(A + (size_t)gr * DD))[c4]
                        : make_float4(0.f, 0.f, 0.f, 0.f);
    ((float4*)As[r])[c4] = v;
  }
  __syncthreads();
  int cg = t & 31, rp = t >> 5;
  int r0 = rp * 2, r1 = r0 + 1;
  float a0acc0 = 0, a0acc1 = 0, a0acc2 = 0, a0acc3 = 0;
  float a1acc0 = 0, a1acc1 = 0, a1acc2 = 0, a1acc3 = 0;
#pragma unroll 8
  for (int k = 0; k < DD; ++k) {
    float4 w4 = ((const float4*)(Ws + k * DD))[cg];
    float a0 = As[r0][k], a1 = As[r1][k];
    a0acc0 += a0 * w4.x; a0acc1 += a0 * w4.y; a0acc2 += a0 * w4.z; a0acc3 += a0 * w4.w;
    a1acc0 += a1 * w4.x; a1acc1 += a1 * w4.y; a1acc2 += a1 * w4.z; a1acc3 += a1 * w4.w;
  }
  int c0 = cg * 4;
  float4 o0, o1;
  o0.x = fmaxf(a0acc0 * al[c0 + 0] + bb[c0 + 0], 0.f);
  o0.y = fmaxf(a0acc1 * al[c0 + 1] + bb[c0 + 1], 0.f);
  o0.z = fmaxf(a0acc2 * al[c0 + 2] + bb[c0 + 2], 0.f);
  o0.w = fmaxf(a0acc3 * al[c0 + 3] + bb[c0 + 3], 0.f);
  o1.x = fmaxf(a1acc0 * al[c0 + 0] + bb[c0 + 0], 0.f);
  o1.y = fmaxf(a1acc1 * al[c0 + 1] + bb[c0 + 1], 0.f);
  o1.z = fmaxf(a1acc2 * al[c0 + 2] + bb[c0 + 2], 0.f);
  o1.w = fmaxf(a1acc3 * al[c0 + 3] + bb[c0 + 3], 0.f);
  int gr0 = row0 + r0, gr1 = row0 + r1;
  if (gr0 < N) *((float4*)(out + (size_t)gr0 * DD + c0)) = o0;
  if (gr1 < N) *((float4*)(out + (size_t)gr1 * DD + c0)) = o1;
}

// sums[batch[n]] += h[n]; cnt[batch[n]] += 1
__global__ __launch_bounds__(256) void k_pool(const float* __restrict__ h,
                                              const int* __restrict__ batch,
                                              float* __restrict__ sums,
                                              float* __restrict__ cnt) {
  int t = blockIdx.x * 256 + threadIdx.x;
  int n = t >> 5;
  if (n >= NN) return;
  int lane = t & 31;
  int b = batch[n];
  float4 v = ((const float4*)(h + (size_t)n * DD))[lane];
  float* dp = sums + (size_t)b * DD + lane * 4;
  atomicAdd(dp + 0, v.x);
  atomicAdd(dp + 1, v.y);
  atomicAdd(dp + 2, v.z);
  atomicAdd(dp + 3, v.w);
  if (lane == 0) atomicAdd(cnt + b, 1.0f);
}

// pooled mean -> relu(bn(@wc1)) -> @wc2 + bc2 ; one block per graph
__global__ __launch_bounds__(128) void k_cls(const float* __restrict__ sums,
                                             const float* __restrict__ cnt,
                                             const float* __restrict__ wc1,
                                             const float* __restrict__ bc1,
                                             const float* __restrict__ gc1,
                                             const float* __restrict__ bec1,
                                             const float* __restrict__ mc1,
                                             const float* __restrict__ vc1,
                                             const float* __restrict__ wc2,
                                             const float* __restrict__ bc2,
                                             float* __restrict__ outp) {
  __shared__ float p[DD];
  __shared__ float hh[64];
  int g = blockIdx.x, t = threadIdx.x;
  float inv = 1.0f / fmaxf(cnt[g], 1.0f);
  p[t] = sums[(size_t)g * DD + t] * inv;
  __syncthreads();
  if (t < 64) {
    float acc = 0.f;
#pragma unroll 8
    for (int k = 0; k < DD; ++k) acc += p[k] * wc1[k * 64 + t];
    float a = gc1[t] * rsqrtf(vc1[t] + EPS);
    float b2 = (bc1[t] - mc1[t]) * a + bec1[t];
    hh[t] = fmaxf(acc * a + b2, 0.f);
  }
  __syncthreads();
  if (t < 2) {
    float acc = bc2[t];
#pragma unroll
    for (int k = 0; k < 64; ++k) acc += hh[k] * wc2[k * 2 + t];
    outp[g * 2 + t] = acc;
  }
}

extern "C" void kernel_launch(void* const* d_in, const int* in_sizes, int n_in,
                              void* d_out, int out_size, void* d_ws, size_t ws_size,
                              hipStream_t stream) {
  const float* x = (const float*)d_in[0];
  const int* ei = (const int*)d_in[1];
  const int* batch = (const int*)d_in[2];
  const float* w11 = (const float*)d_in[3];
  const float* b11 = (const float*)d_in[4];
  const float* g11 = (const float*)d_in[5];
  const float* be11 = (const float*)d_in[6];
  const float* m11 = (const float*)d_in[7];
  const float* v11 = (const float*)d_in[8];
  const float* w12 = (const float*)d_in[9];
  const float* b12 = (const float*)d_in[10];
  const float* g12 = (const float*)d_in[11];
  const float* be12 = (const float*)d_in[12];
  const float* m12 = (const float*)d_in[13];
  const float* v12 = (const float*)d_in[14];
  const float* w21 = (const float*)d_in[15];
  const float* b21 = (const float*)d_in[16];
  const float* g21 = (const float*)d_in[17];
  const float* be21 = (const float*)d_in[18];
  const float* m21 = (const float*)d_in[19];
  const float* v21 = (const float*)d_in[20];
  const float* w22 = (const float*)d_in[21];
  const float* b22 = (const float*)d_in[22];
  const float* g22 = (const float*)d_in[23];
  const float* be22 = (const float*)d_in[24];
  const float* m22 = (const float*)d_in[25];
  const float* v22 = (const float*)d_in[26];
  const float* wc1 = (const float*)d_in[27];
  const float* bc1 = (const float*)d_in[28];
  const float* gc1 = (const float*)d_in[29];
  const float* bec1 = (const float*)d_in[30];
  const float* mc1 = (const float*)d_in[31];
  const float* vc1 = (const float*)d_in[32];
  const float* wc2 = (const float*)d_in[33];
  const float* bc2 = (const float*)d_in[34];

  const size_t NB = (size_t)NN * DD;
  float* B1 = (float*)d_ws;
  float* B2 = B1 + NB;
  float* B3 = B2 + NB;
  float* sums = B3 + NB;
  float* cnt = sums + (size_t)GG * DD;

  const int n4 = NN * DD / 4;
  const int cpyBlocks = (n4 + 255) / 256;
  const int scatBlocks = (NE * 32) / 256;
  const int gemmBlocks = NN / 16;  // 50000/16 = 3125 exact

  // ---- GIN layer 1 ----
  k_copy<<<cpyBlocks, 256, 0, stream>>>((const float4*)x, (float4*)B1, n4);
  k_scatter<<<scatBlocks, 256, 0, stream>>>(x, ei, B1);
  k_gemm128<<<gemmBlocks, 256, 0, stream>>>(B1, w11, b11, g11, be11, m11, v11, B2, NN);
  k_gemm128<<<gemmBlocks, 256, 0, stream>>>(B2, w12, b12, g12, be12, m12, v12, B3, NN);

  // ---- GIN layer 2 ----
  k_copy<<<cpyBlocks, 256, 0, stream>>>((const float4*)B3, (float4*)B1, n4);
  k_scatter<<<scatBlocks, 256, 0, stream>>>(B3, ei, B1);
  k_gemm128<<<gemmBlocks, 256, 0, stream>>>(B1, w21, b21, g21, be21, m21, v21, B2, NN);
  k_gemm128<<<gemmBlocks, 256, 0, stream>>>(B2, w22, b22, g22, be22, m22, v22, B3, NN);

  // ---- global mean pool + classifier ----
  hipMemsetAsync(sums, 0, (size_t)(GG * DD + GG) * sizeof(float), stream);
  k_pool<<<(NN * 32 + 255) / 256, 256, 0, stream>>>(B3, batch, sums, cnt);
  k_cls<<<GG, 128, 0, stream>>>(sums, cnt, wc1, bc1, gc1, bec1, mc1, vc1, wc2, bc2,
                                (float*)d_out);
}

// Round 2
// 410.288 us; speedup vs baseline: 7.3087x; 7.3087x over previous
//
#include <hip/hip_runtime.h>

#define NN 50000
#define NE 800000
#define DD 128
#define GG 2048
#define EPS 1e-5f
#define NSCAN 49  // ceil(NN/1024)

// ---------------- CSR build ----------------
__global__ __launch_bounds__(256) void k_hist(const int* __restrict__ ei,
                                              int* __restrict__ deg) {
  int e = blockIdx.x * 256 + threadIdx.x;
  if (e < NE) atomicAdd(&deg[ei[NE + e]], 1);
}

// block scans 1024 nodes (4/thread); writes block-local exclusive into row_ptr
__global__ __launch_bounds__(256) void k_scan1(const int* __restrict__ deg,
                                               int* __restrict__ row_ptr,
                                               int* __restrict__ part) {
  __shared__ int buf[256];
  int t = threadIdx.x;
  int base = blockIdx.x * 1024 + t * 4;
  int v0 = (base + 0 < NN) ? deg[base + 0] : 0;
  int v1 = (base + 1 < NN) ? deg[base + 1] : 0;
  int v2 = (base + 2 < NN) ? deg[base + 2] : 0;
  int v3 = (base + 3 < NN) ? deg[base + 3] : 0;
  int tot = v0 + v1 + v2 + v3;
  buf[t] = tot;
  __syncthreads();
  int sum = tot;
  for (int off = 1; off < 256; off <<= 1) {
    int o = (t >= off) ? buf[t - off] : 0;
    __syncthreads();
    sum += o;
    buf[t] = sum;
    __syncthreads();
  }
  int ex = sum - tot;
  if (base + 0 < NN) row_ptr[base + 0] = ex;
  if (base + 1 < NN) row_ptr[base + 1] = ex + v0;
  if (base + 2 < NN) row_ptr[base + 2] = ex + v0 + v1;
  if (base + 3 < NN) row_ptr[base + 3] = ex + v0 + v1 + v2;
  if (t == 255) part[blockIdx.x] = sum;
}

__global__ void k_scan2(int* __restrict__ part) {
  int run = 0;
  for (int i = 0; i < NSCAN; ++i) {
    int v = part[i];
    part[i] = run;
    run += v;
  }
}

__global__ __launch_bounds__(256) void k_scan3(int* __restrict__ row_ptr,
                                               const int* __restrict__ part,
                                               int* __restrict__ fill_pos) {
  int i = blockIdx.x * 256 + threadIdx.x;
  if (i < NN) {
    int v = row_ptr[i] + part[i >> 10];
    row_ptr[i] = v;
    fill_pos[i] = v;
  }
  if (i == 0) row_ptr[NN] = NE;
}

__global__ __launch_bounds__(256) void k_fill(const int* __restrict__ ei,
                                              int* __restrict__ fill_pos,
                                              int* __restrict__ csr_src) {
  int e = blockIdx.x * 256 + threadIdx.x;
  if (e >= NE) return;
  int s = ei[e], d = ei[NE + e];
  int p = atomicAdd(&fill_pos[d], 1);
  csr_src[p] = s;
}

// ---------------- aggregation: out[n] = x[n] + sum_{j in N(n)} x[j] ----------------
// one wave (64 lanes) per node; lane owns 2 columns (float2)
__global__ __launch_bounds__(256) void k_agg(const float* __restrict__ x,
                                             const int* __restrict__ row_ptr,
                                             const int* __restrict__ csr_src,
                                             float* __restrict__ out) {
  int node = (blockIdx.x * 256 + threadIdx.x) >> 6;
  if (node >= NN) return;
  int lane = threadIdx.x & 63;
  size_t coff = (size_t)lane * 2;
  float2 acc = *(const float2*)(x + (size_t)node * DD + coff);
  int beg = row_ptr[node], end = row_ptr[node + 1];
  for (int i = beg; i < end; i += 64) {
    int idx = i + lane;
    int my = (idx < end) ? csr_src[idx] : 0;
    int cnt = min(64, end - i);
    for (int j = 0; j < cnt; ++j) {
      int s = __shfl(my, j);
      float2 v = *(const float2*)(x + (size_t)s * DD + coff);
      acc.x += v.x;
      acc.y += v.y;
    }
  }
  *(float2*)(out + (size_t)node * DD + coff) = acc;
}

// ---------------- GEMM: out = relu(bn(A@W + bias)) ----------------
__global__ __launch_bounds__(256) void k_gemm128(const float* __restrict__ A,
                                                 const float* __restrict__ W,
                                                 const float* __restrict__ bias,
                                                 const float* __restrict__ gam,
                                                 const float* __restrict__ bet,
                                                 const float* __restrict__ mu,
                                                 const float* __restrict__ var,
                                                 float* __restrict__ out, int N) {
  __shared__ float Ws[DD * DD];
  __shared__ float As[16][DD];
  __shared__ float al[DD], bb[DD];
  int t = threadIdx.x;
  for (int i = t; i < DD * DD; i += 256) Ws[i] = W[i];
  if (t < DD) {
    float a = gam[t] * rsqrtf(var[t] + EPS);
    al[t] = a;
    bb[t] = (bias[t] - mu[t]) * a + bet[t];
  }
  int row0 = blockIdx.x * 16;
  for (int i = t; i < 16 * 32; i += 256) {
    int r = i >> 5, c4 = i & 31;
    int gr = row0 + r;
    float4 v = (gr < N) ? ((const float4*)(A + (size_t)gr * DD))[c4]
                        : make_float4(0.f, 0.f, 0.f, 0.f);
    ((float4*)As[r])[c4] = v;
  }
  __syncthreads();
  int cg = t & 31, rp = t >> 5;
  int r0 = rp * 2, r1 = r0 + 1;
  float a0acc0 = 0, a0acc1 = 0, a0acc2 = 0, a0acc3 = 0;
  float a1acc0 = 0, a1acc1 = 0, a1acc2 = 0, a1acc3 = 0;
#pragma unroll 8
  for (int k = 0; k < DD; ++k) {
    float4 w4 = ((const float4*)(Ws + k * DD))[cg];
    float a0 = As[r0][k], a1 = As[r1][k];
    a0acc0 += a0 * w4.x; a0acc1 += a0 * w4.y; a0acc2 += a0 * w4.z; a0acc3 += a0 * w4.w;
    a1acc0 += a1 * w4.x; a1acc1 += a1 * w4.y; a1acc2 += a1 * w4.z; a1acc3 += a1 * w4.w;
  }
  int c0 = cg * 4;
  float4 o0, o1;
  o0.x = fmaxf(a0acc0 * al[c0 + 0] + bb[c0 + 0], 0.f);
  o0.y = fmaxf(a0acc1 * al[c0 + 1] + bb[c0 + 1], 0.f);
  o0.z = fmaxf(a0acc2 * al[c0 + 2] + bb[c0 + 2], 0.f);
  o0.w = fmaxf(a0acc3 * al[c0 + 3] + bb[c0 + 3], 0.f);
  o1.x = fmaxf(a1acc0 * al[c0 + 0] + bb[c0 + 0], 0.f);
  o1.y = fmaxf(a1acc1 * al[c0 + 1] + bb[c0 + 1], 0.f);
  o1.z = fmaxf(a1acc2 * al[c0 + 2] + bb[c0 + 2], 0.f);
  o1.w = fmaxf(a1acc3 * al[c0 + 3] + bb[c0 + 3], 0.f);
  int gr0 = row0 + r0, gr1 = row0 + r1;
  if (gr0 < N) *((float4*)(out + (size_t)gr0 * DD + c0)) = o0;
  if (gr1 < N) *((float4*)(out + (size_t)gr1 * DD + c0)) = o1;
}

// ---------------- fused mean-pool + classifier (batch is sorted) ----------------
__device__ __forceinline__ int lb(const int* __restrict__ a, int n, int v) {
  int lo = 0, hi = n;
  while (lo < hi) {
    int mid = (lo + hi) >> 1;
    if (a[mid] < v) lo = mid + 1;
    else hi = mid;
  }
  return lo;
}

__global__ __launch_bounds__(128) void k_poolcls(const float* __restrict__ h,
                                                 const int* __restrict__ batch,
                                                 const float* __restrict__ wc1,
                                                 const float* __restrict__ bc1,
                                                 const float* __restrict__ gc1,
                                                 const float* __restrict__ bec1,
                                                 const float* __restrict__ mc1,
                                                 const float* __restrict__ vc1,
                                                 const float* __restrict__ wc2,
                                                 const float* __restrict__ bc2,
                                                 float* __restrict__ outp) {
  __shared__ int sb[2];
  __shared__ float ps[DD];
  __shared__ float hh[64];
  int g = blockIdx.x, t = threadIdx.x;
  if (t < 2) sb[t] = lb(batch, NN, g + t);
  __syncthreads();
  int beg = sb[0], end = sb[1];
  float acc = 0.f;
  for (int n = beg; n < end; ++n) acc += h[(size_t)n * DD + t];
  float inv = 1.0f / fmaxf((float)(end - beg), 1.0f);
  ps[t] = acc * inv;
  __syncthreads();
  if (t < 64) {
    float a2 = 0.f;
#pragma unroll 8
    for (int k = 0; k < DD; ++k) a2 += ps[k] * wc1[k * 64 + t];
    float a = gc1[t] * rsqrtf(vc1[t] + EPS);
    float b2 = (bc1[t] - mc1[t]) * a + bec1[t];
    hh[t] = fmaxf(a2 * a + b2, 0.f);
  }
  __syncthreads();
  if (t < 2) {
    float a2 = bc2[t];
#pragma unroll
    for (int k = 0; k < 64; ++k) a2 += hh[k] * wc2[k * 2 + t];
    outp[g * 2 + t] = a2;
  }
}

extern "C" void kernel_launch(void* const* d_in, const int* in_sizes, int n_in,
                              void* d_out, int out_size, void* d_ws, size_t ws_size,
                              hipStream_t stream) {
  const float* x = (const float*)d_in[0];
  const int* ei = (const int*)d_in[1];
  const int* batch = (const int*)d_in[2];
  const float* w11 = (const float*)d_in[3];
  const float* b11 = (const float*)d_in[4];
  const float* g11 = (const float*)d_in[5];
  const float* be11 = (const float*)d_in[6];
  const float* m11 = (const float*)d_in[7];
  const float* v11 = (const float*)d_in[8];
  const float* w12 = (const float*)d_in[9];
  const float* b12 = (const float*)d_in[10];
  const float* g12 = (const float*)d_in[11];
  const float* be12 = (const float*)d_in[12];
  const float* m12 = (const float*)d_in[13];
  const float* v12 = (const float*)d_in[14];
  const float* w21 = (const float*)d_in[15];
  const float* b21 = (const float*)d_in[16];
  const float* g21 = (const float*)d_in[17];
  const float* be21 = (const float*)d_in[18];
  const float* m21 = (const float*)d_in[19];
  const float* v21 = (const float*)d_in[20];
  const float* w22 = (const float*)d_in[21];
  const float* b22 = (const float*)d_in[22];
  const float* g22 = (const float*)d_in[23];
  const float* be22 = (const float*)d_in[24];
  const float* m22 = (const float*)d_in[25];
  const float* v22 = (const float*)d_in[26];
  const float* wc1 = (const float*)d_in[27];
  const float* bc1 = (const float*)d_in[28];
  const float* gc1 = (const float*)d_in[29];
  const float* bec1 = (const float*)d_in[30];
  const float* mc1 = (const float*)d_in[31];
  const float* vc1 = (const float*)d_in[32];
  const float* wc2 = (const float*)d_in[33];
  const float* bc2 = (const float*)d_in[34];

  const size_t NB = (size_t)NN * DD;
  float* B1 = (float*)d_ws;
  float* B2 = B1 + NB;
  float* B3 = B2 + NB;
  int* row_ptr = (int*)(B3 + NB);      // NN+1
  int* fill_pos = row_ptr + NN + 1;    // NN
  int* deg = fill_pos + NN;            // NN
  int* part = deg + NN;                // NSCAN (pad 64)
  int* csr_src = part + 64;            // NE

  const int edgeBlocks = (NE + 255) / 256;  // 3125
  const int gemmBlocks = NN / 16;           // 3125
  const int aggBlocks = NN * 64 / 256;      // 12500

  // ---- CSR build (once; both layers share the graph) ----
  hipMemsetAsync(deg, 0, NN * sizeof(int), stream);
  k_hist<<<edgeBlocks, 256, 0, stream>>>(ei, deg);
  k_scan1<<<NSCAN, 256, 0, stream>>>(deg, row_ptr, part);
  k_scan2<<<1, 1, 0, stream>>>(part);
  k_scan3<<<(NN + 255) / 256, 256, 0, stream>>>(row_ptr, part, fill_pos);
  k_fill<<<edgeBlocks, 256, 0, stream>>>(ei, fill_pos, csr_src);

  // ---- GIN layer 1 ----
  k_agg<<<aggBlocks, 256, 0, stream>>>(x, row_ptr, csr_src, B1);
  k_gemm128<<<gemmBlocks, 256, 0, stream>>>(B1, w11, b11, g11, be11, m11, v11, B2, NN);
  k_gemm128<<<gemmBlocks, 256, 0, stream>>>(B2, w12, b12, g12, be12, m12, v12, B3, NN);

  // ---- GIN layer 2 ----
  k_agg<<<aggBlocks, 256, 0, stream>>>(B3, row_ptr, csr_src, B1);
  k_gemm128<<<gemmBlocks, 256, 0, stream>>>(B1, w21, b21, g21, be21, m21, v21, B2, NN);
  k_gemm128<<<gemmBlocks, 256, 0, stream>>>(B2, w22, b22, g22, be22, m22, v22, B3, NN);

  // ---- fused mean pool + classifier ----
  k_poolcls<<<GG, 128, 0, stream>>>(B3, batch, wc1, bc1, gc1, bec1, mc1, vc1,
                                    wc2, bc2, (float*)d_out);
}

// Round 3
// 289.664 us; speedup vs baseline: 10.3522x; 1.4164x over previous
//
#include <hip/hip_runtime.h>

#define NN 50000
#define NE 800000
#define DD 128
#define GG 2048
#define EPS 1e-5f
#define NSCAN 49  // ceil(NN/1024)

typedef __attribute__((ext_vector_type(8))) short short8;
typedef __attribute__((ext_vector_type(4))) float floatx4;

__device__ __forceinline__ ushort f2b(float f) {  // fp32 -> bf16 RNE
  uint u = __float_as_uint(f);
  uint r = ((u >> 16) & 1u) + 0x7fffu;
  return (ushort)((u + r) >> 16);
}
__device__ __forceinline__ float b2f(ushort h) {
  return __uint_as_float(((uint)h) << 16);
}
__device__ __forceinline__ float blo(uint u) { return __uint_as_float(u << 16); }
__device__ __forceinline__ float bhi(uint u) { return __uint_as_float(u & 0xffff0000u); }

// ---------------- fp32 -> bf16 convert ----------------
__global__ __launch_bounds__(256) void k_cvt(const float4* __restrict__ x,
                                             short8* __restrict__ out, int n8) {
  int i = blockIdx.x * 256 + threadIdx.x;
  if (i >= n8) return;
  float4 a = x[2 * i], b = x[2 * i + 1];
  short8 v;
  v[0] = (short)f2b(a.x); v[1] = (short)f2b(a.y);
  v[2] = (short)f2b(a.z); v[3] = (short)f2b(a.w);
  v[4] = (short)f2b(b.x); v[5] = (short)f2b(b.y);
  v[6] = (short)f2b(b.z); v[7] = (short)f2b(b.w);
  out[i] = v;
}

// ---------------- CSR build ----------------
__global__ __launch_bounds__(256) void k_hist(const int* __restrict__ ei,
                                              int* __restrict__ deg) {
  int e = blockIdx.x * 256 + threadIdx.x;
  if (e < NE) atomicAdd(&deg[ei[NE + e]], 1);
}

__global__ __launch_bounds__(256) void k_scan1(const int* __restrict__ deg,
                                               int* __restrict__ row_ptr,
                                               int* __restrict__ part) {
  __shared__ int buf[256];
  int t = threadIdx.x;
  int base = blockIdx.x * 1024 + t * 4;
  int v0 = (base + 0 < NN) ? deg[base + 0] : 0;
  int v1 = (base + 1 < NN) ? deg[base + 1] : 0;
  int v2 = (base + 2 < NN) ? deg[base + 2] : 0;
  int v3 = (base + 3 < NN) ? deg[base + 3] : 0;
  int tot = v0 + v1 + v2 + v3;
  buf[t] = tot;
  __syncthreads();
  int sum = tot;
  for (int off = 1; off < 256; off <<= 1) {
    int o = (t >= off) ? buf[t - off] : 0;
    __syncthreads();
    sum += o;
    buf[t] = sum;
    __syncthreads();
  }
  int ex = sum - tot;
  if (base + 0 < NN) row_ptr[base + 0] = ex;
  if (base + 1 < NN) row_ptr[base + 1] = ex + v0;
  if (base + 2 < NN) row_ptr[base + 2] = ex + v0 + v1;
  if (base + 3 < NN) row_ptr[base + 3] = ex + v0 + v1 + v2;
  if (t == 255) part[blockIdx.x] = sum;
}

__global__ void k_scan2(int* __restrict__ part) {
  int run = 0;
  for (int i = 0; i < NSCAN; ++i) {
    int v = part[i];
    part[i] = run;
    run += v;
  }
}

__global__ __launch_bounds__(256) void k_scan3(int* __restrict__ row_ptr,
                                               const int* __restrict__ part,
                                               int* __restrict__ fill_pos) {
  int i = blockIdx.x * 256 + threadIdx.x;
  if (i < NN) {
    int v = row_ptr[i] + part[i >> 10];
    row_ptr[i] = v;
    fill_pos[i] = v;
  }
  if (i == 0) row_ptr[NN] = NE;
}

__global__ __launch_bounds__(256) void k_fill(const int* __restrict__ ei,
                                              int* __restrict__ fill_pos,
                                              int* __restrict__ csr_src) {
  int e = blockIdx.x * 256 + threadIdx.x;
  if (e >= NE) return;
  int s = ei[e], d = ei[NE + e];
  int p = atomicAdd(&fill_pos[d], 1);
  csr_src[p] = s;
}

// ---------------- aggregation (bf16): out[n] = x[n] + sum_{j->n} x[j] ----------------
// one wave per node; lane owns 2 cols packed in one uint
__global__ __launch_bounds__(256) void k_agg(const uint* __restrict__ X,
                                             const int* __restrict__ row_ptr,
                                             const int* __restrict__ csr_src,
                                             uint* __restrict__ out) {
  int node = (blockIdx.x * 256 + threadIdx.x) >> 6;
  if (node >= NN) return;
  int lane = threadIdx.x & 63;
  uint s0 = X[(size_t)node * 64 + lane];
  float ax = blo(s0), ay = bhi(s0);
  int beg = row_ptr[node], end = row_ptr[node + 1];
  for (int i = beg; i < end; i += 64) {
    int idx = i + lane;
    int my = (idx < end) ? csr_src[idx] : 0;
    int cnt = min(64, end - i);
    for (int j = 0; j < cnt; ++j) {
      int s = __shfl(my, j);
      uint v = X[(size_t)s * 64 + lane];
      ax += blo(v);
      ay += bhi(v);
    }
  }
  out[(size_t)node * 64 + lane] = (uint)f2b(ax) | ((uint)f2b(ay) << 16);
}

// ---------------- MFMA GEMM: out = relu(bn(A@W + bias)), bf16 in/out ----------------
// 256 thr = 4 waves, 64 rows/block, full 128 cols per wave
__global__ __launch_bounds__(256) void k_gemm(const ushort* __restrict__ A,
                                              const float* __restrict__ W,
                                              const float* __restrict__ bias,
                                              const float* __restrict__ gam,
                                              const float* __restrict__ bet,
                                              const float* __restrict__ mu,
                                              const float* __restrict__ var,
                                              ushort* __restrict__ out) {
  __shared__ ushort Wt[DD * DD];  // transposed + XOR-swizzled, 32 KB
  __shared__ float al[DD], bb[DD];
  int t = threadIdx.x;
  // stage W^T (c-major) as bf16; swizzle k with ((c&7)<<3) to break bank conflicts
  for (int ii = t; ii < 4096; ii += 256) {
    int c = ii & 127, k0 = (ii >> 7) * 4;
    float w0 = W[(k0 + 0) * DD + c];
    float w1 = W[(k0 + 1) * DD + c];
    float w2 = W[(k0 + 2) * DD + c];
    float w3 = W[(k0 + 3) * DD + c];
    ushort4 p;
    p.x = f2b(w0); p.y = f2b(w1); p.z = f2b(w2); p.w = f2b(w3);
    *(ushort4*)&Wt[c * DD + (k0 ^ ((c & 7) << 3))] = p;
  }
  if (t < DD) {
    float a = gam[t] * rsqrtf(var[t] + EPS);
    al[t] = a;
    bb[t] = (bias[t] - mu[t]) * a + bet[t];
  }
  __syncthreads();

  int w = t >> 6, l = t & 63;
  int lr = l & 15, lg = l >> 4;
  int rowBase = blockIdx.x * 64 + w * 16;
  const short8* Ar = (const short8*)(A + (size_t)(rowBase + lr) * DD);
  short8 a0 = Ar[0 * 4 + lg];
  short8 a1 = Ar[1 * 4 + lg];
  short8 a2 = Ar[2 * 4 + lg];
  short8 a3 = Ar[3 * 4 + lg];

#pragma unroll
  for (int ct = 0; ct < 8; ++ct) {
    int c = ct * 16 + lr;
    int sw = (c & 7) << 3;
    const ushort* wr = Wt + c * DD;
    short8 b0 = *(const short8*)(wr + ((0 * 32 + lg * 8) ^ sw));
    short8 b1 = *(const short8*)(wr + ((1 * 32 + lg * 8) ^ sw));
    short8 b2 = *(const short8*)(wr + ((2 * 32 + lg * 8) ^ sw));
    short8 b3 = *(const short8*)(wr + ((3 * 32 + lg * 8) ^ sw));
    floatx4 acc = {0.f, 0.f, 0.f, 0.f};
    acc = __builtin_amdgcn_mfma_f32_16x16x32_bf16(a0, b0, acc, 0, 0, 0);
    acc = __builtin_amdgcn_mfma_f32_16x16x32_bf16(a1, b1, acc, 0, 0, 0);
    acc = __builtin_amdgcn_mfma_f32_16x16x32_bf16(a2, b2, acc, 0, 0, 0);
    acc = __builtin_amdgcn_mfma_f32_16x16x32_bf16(a3, b3, acc, 0, 0, 0);
    float alc = al[c], bbc = bb[c];
#pragma unroll
    for (int reg = 0; reg < 4; ++reg) {
      int r = rowBase + lg * 4 + reg;
      if (r < NN) {
        float o = fmaxf(acc[reg] * alc + bbc, 0.f);
        out[(size_t)r * DD + c] = f2b(o);
      }
    }
  }
}

// ---------------- fused mean-pool + classifier (batch sorted) ----------------
__device__ __forceinline__ int lb(const int* __restrict__ a, int n, int v) {
  int lo = 0, hi = n;
  while (lo < hi) {
    int mid = (lo + hi) >> 1;
    if (a[mid] < v) lo = mid + 1;
    else hi = mid;
  }
  return lo;
}

__global__ __launch_bounds__(128) void k_poolcls(const ushort* __restrict__ h,
                                                 const int* __restrict__ batch,
                                                 const float* __restrict__ wc1,
                                                 const float* __restrict__ bc1,
                                                 const float* __restrict__ gc1,
                                                 const float* __restrict__ bec1,
                                                 const float* __restrict__ mc1,
                                                 const float* __restrict__ vc1,
                                                 const float* __restrict__ wc2,
                                                 const float* __restrict__ bc2,
                                                 float* __restrict__ outp) {
  __shared__ int sb[2];
  __shared__ float ps[DD];
  __shared__ float hh[64];
  int g = blockIdx.x, t = threadIdx.x;
  if (t < 2) sb[t] = lb(batch, NN, g + t);
  __syncthreads();
  int beg = sb[0], end = sb[1];
  float acc = 0.f;
  for (int n = beg; n < end; ++n) acc += b2f(h[(size_t)n * DD + t]);
  float inv = 1.0f / fmaxf((float)(end - beg), 1.0f);
  ps[t] = acc * inv;
  __syncthreads();
  if (t < 64) {
    float a2 = 0.f;
#pragma unroll 8
    for (int k = 0; k < DD; ++k) a2 += ps[k] * wc1[k * 64 + t];
    float a = gc1[t] * rsqrtf(vc1[t] + EPS);
    float b2 = (bc1[t] - mc1[t]) * a + bec1[t];
    hh[t] = fmaxf(a2 * a + b2, 0.f);
  }
  __syncthreads();
  if (t < 2) {
    float a2 = bc2[t];
#pragma unroll
    for (int k = 0; k < 64; ++k) a2 += hh[k] * wc2[k * 2 + t];
    outp[g * 2 + t] = a2;
  }
}

extern "C" void kernel_launch(void* const* d_in, const int* in_sizes, int n_in,
                              void* d_out, int out_size, void* d_ws, size_t ws_size,
                              hipStream_t stream) {
  const float* x = (const float*)d_in[0];
  const int* ei = (const int*)d_in[1];
  const int* batch = (const int*)d_in[2];
  const float* w11 = (const float*)d_in[3];
  const float* b11 = (const float*)d_in[4];
  const float* g11 = (const float*)d_in[5];
  const float* be11 = (const float*)d_in[6];
  const float* m11 = (const float*)d_in[7];
  const float* v11 = (const float*)d_in[8];
  const float* w12 = (const float*)d_in[9];
  const float* b12 = (const float*)d_in[10];
  const float* g12 = (const float*)d_in[11];
  const float* be12 = (const float*)d_in[12];
  const float* m12 = (const float*)d_in[13];
  const float* v12 = (const float*)d_in[14];
  const float* w21 = (const float*)d_in[15];
  const float* b21 = (const float*)d_in[16];
  const float* g21 = (const float*)d_in[17];
  const float* be21 = (const float*)d_in[18];
  const float* m21 = (const float*)d_in[19];
  const float* v21 = (const float*)d_in[20];
  const float* w22 = (const float*)d_in[21];
  const float* b22 = (const float*)d_in[22];
  const float* g22 = (const float*)d_in[23];
  const float* be22 = (const float*)d_in[24];
  const float* m22 = (const float*)d_in[25];
  const float* v22 = (const float*)d_in[26];
  const float* wc1 = (const float*)d_in[27];
  const float* bc1 = (const float*)d_in[28];
  const float* gc1 = (const float*)d_in[29];
  const float* bec1 = (const float*)d_in[30];
  const float* mc1 = (const float*)d_in[31];
  const float* vc1 = (const float*)d_in[32];
  const float* wc2 = (const float*)d_in[33];
  const float* bc2 = (const float*)d_in[34];

  const size_t NB = (size_t)NN * DD;  // ushort elements per feature buffer
  ushort* XB = (ushort*)d_ws;
  ushort* AG = XB + NB;
  ushort* T1 = AG + NB;
  ushort* H1 = T1 + NB;
  ushort* H2 = H1 + NB;
  int* row_ptr = (int*)(H2 + NB);    // NN+1
  int* fill_pos = row_ptr + NN + 1;  // NN
  int* deg = fill_pos + NN;          // NN
  int* part = deg + NN;              // NSCAN (pad 64)
  int* csr_src = part + 64;          // NE

  const int edgeBlocks = (NE + 255) / 256;
  const int gemmBlocks = (NN + 63) / 64;  // 782
  const int aggBlocks = NN / 4;           // 12500
  const int cvtBlocks = (int)(NB / 8 / 256);  // 3125

  // ---- CSR build + input conversion ----
  hipMemsetAsync(deg, 0, NN * sizeof(int), stream);
  k_hist<<<edgeBlocks, 256, 0, stream>>>(ei, deg);
  k_cvt<<<cvtBlocks, 256, 0, stream>>>((const float4*)x, (short8*)XB, (int)(NB / 8));
  k_scan1<<<NSCAN, 256, 0, stream>>>(deg, row_ptr, part);
  k_scan2<<<1, 1, 0, stream>>>(part);
  k_scan3<<<(NN + 255) / 256, 256, 0, stream>>>(row_ptr, part, fill_pos);
  k_fill<<<edgeBlocks, 256, 0, stream>>>(ei, fill_pos, csr_src);

  // ---- GIN layer 1 ----
  k_agg<<<aggBlocks, 256, 0, stream>>>((const uint*)XB, row_ptr, csr_src, (uint*)AG);
  k_gemm<<<gemmBlocks, 256, 0, stream>>>(AG, w11, b11, g11, be11, m11, v11, T1);
  k_gemm<<<gemmBlocks, 256, 0, stream>>>(T1, w12, b12, g12, be12, m12, v12, H1);

  // ---- GIN layer 2 ----
  k_agg<<<aggBlocks, 256, 0, stream>>>((const uint*)H1, row_ptr, csr_src, (uint*)AG);
  k_gemm<<<gemmBlocks, 256, 0, stream>>>(AG, w21, b21, g21, be21, m21, v21, T1);
  k_gemm<<<gemmBlocks, 256, 0, stream>>>(T1, w22, b22, g22, be22, m22, v22, H2);

  // ---- fused mean pool + classifier ----
  k_poolcls<<<GG, 128, 0, stream>>>(H2, batch, wc1, bc1, gc1, bec1, mc1, vc1,
                                    wc2, bc2, (float*)d_out);
}